// Round 2
// baseline (3961.359 us; speedup 1.0000x reference)
//
#include <hip/hip_runtime.h>
#include <hip/hip_bf16.h>
#include <hip/hip_fp16.h>

// LSTM, T=64. Structure:
//   prep_w : Wx[2048][512], Wh[2048][512] bf16 (gate-interleaved n=4h+g, K-transposed), biasr.
//            Also zeroes the 64 grid-barrier counters.
//   prep_x : Xbf[t][b][512] bf16 (time-major).
//   zx_gemm: zx[t][b][2048] = Xbf @ Wx^T, fp16 storage (parallel, off the critical path).
//   lstm_persist: ONE plain-launched persistent kernel, 512 blocks (16 m x 32 n, 2/CU),
//            all 64 steps with a hand-rolled device-scope grid barrier between them
//            (hipLaunchCooperativeKernel is not graph-capturable -> silently dropped in R1).
//            c-state register-resident; h ping-pongs in Hbuf[0/1]; acquire fence in ALL
//            threads after the barrier emits buffer_inv so stale L1/L2 Hbuf lines
//            (same buffer re-read with period 2) are invalidated.
// LDS staging: global_load_lds width=16 with XOR-swizzled SOURCE permutation
// (phys granule = (seg&8)|((seg^row)&7)) so unpadded frag reads are bank-optimal.
// lstm_persist LDS: Zs unioned with As/Bs (33 KB/block) to guarantee 2 blocks/CU residency.

typedef __attribute__((ext_vector_type(8))) short bfrag8;
typedef __attribute__((ext_vector_type(4))) float facc4;

#define MFMA_B16(a, b, c) __builtin_amdgcn_mfma_f32_16x16x32_bf16(a, b, c, 0, 0, 0)

#define NBLK 512u

__device__ __forceinline__ unsigned short f2bf(float f) {
  unsigned int u = __float_as_uint(f);
  u += 0x7FFFu + ((u >> 16) & 1u);          // RNE
  return (unsigned short)(u >> 16);
}
__device__ __forceinline__ float sigm(float x)  { return 1.0f / (1.0f + __expf(-x)); }
__device__ __forceinline__ float tanh_(float x) { return 1.0f - 2.0f / (__expf(2.0f * x) + 1.0f); }

__device__ __forceinline__ void gl2lds16(const void* g, void* l) {
  __builtin_amdgcn_global_load_lds(
      (const __attribute__((address_space(1))) unsigned int*)g,
      (__attribute__((address_space(3))) unsigned int*)l, 16, 0, 0);
}

// ushort offset of logical granule (row, seg) in a [64 rows][16 segs] swizzled tile.
__device__ __forceinline__ int foff(int row, int seg) {
  return (row << 7) + ((((seg & 8) | ((seg ^ row) & 7))) << 3);
}

// Device-scope grid barrier, one counter slot per step (no reset -> no sense races).
__device__ __forceinline__ void grid_barrier(unsigned int* bar, int slot) {
  __syncthreads();                                   // drains vmcnt: h stores are in L2
  if (threadIdx.x == 0) {
    __builtin_amdgcn_fence(__ATOMIC_RELEASE, "agent");   // wbl2: publish h to coherent point
    __hip_atomic_fetch_add(&bar[slot], 1u, __ATOMIC_RELAXED, __HIP_MEMORY_SCOPE_AGENT);
    while (__hip_atomic_load(&bar[slot], __ATOMIC_RELAXED, __HIP_MEMORY_SCOPE_AGENT) < NBLK)
      __builtin_amdgcn_s_sleep(2);
  }
  __syncthreads();
  __builtin_amdgcn_fence(__ATOMIC_ACQUIRE, "agent");     // buffer_inv: kill stale L1/L2 lines
}

// ---------------- prep kernels ----------------

__global__ void prep_w(const float* __restrict__ Wk, const float* __restrict__ Wr,
                       const float* __restrict__ bias,
                       unsigned short* __restrict__ Wx, unsigned short* __restrict__ Wh,
                       float* __restrict__ biasr, unsigned int* __restrict__ bar)
{
  int gid = (blockIdx.x << 8) + threadIdx.x;   // 0 .. 2M-1
  int k   = gid >> 11;                         // 0..1023
  int col = gid & 2047;                        // original column g*512+h
  float v = (k < 512) ? Wk[((size_t)k << 11) + col]
                      : Wr[((size_t)(k - 512) << 11) + col];
  int n = ((col & 511) << 2) | (col >> 9);     // 4h+g
  if (k < 512) Wx[((size_t)n << 9) + k]         = f2bf(v);
  else         Wh[((size_t)n << 9) + (k - 512)] = f2bf(v);
  if (gid < 2048) biasr[((gid & 511) << 2) | (gid >> 9)] = bias[gid];
  if (gid < 64)   bar[gid] = 0u;               // zero barrier counters each run
}

__global__ void prep_x(const float* __restrict__ x, unsigned short* __restrict__ Xbf)
{
  int flat = (blockIdx.x << 8) + threadIdx.x;  // 0 .. 4,194,303 (granules of 8)
  int d8 = flat & 63;
  int b  = (flat >> 6) & 1023;
  int t  = flat >> 16;
  const float* src = x + ((((size_t)b << 6) + t) << 9) + (d8 << 3);
  float4 v0 = *(const float4*)src;
  float4 v1 = *(const float4*)(src + 4);
  uint4 u;
  u.x = f2bf(v0.x) | ((unsigned)f2bf(v0.y) << 16);
  u.y = f2bf(v0.z) | ((unsigned)f2bf(v0.w) << 16);
  u.z = f2bf(v1.x) | ((unsigned)f2bf(v1.y) << 16);
  u.w = f2bf(v1.z) | ((unsigned)f2bf(v1.w) << 16);
  *(uint4*)&Xbf[((((size_t)t << 10) + b) << 9) + (d8 << 3)] = u;
}

// ---------------- zx precompute GEMM ----------------
// zx[t][b][n] (fp16) = Xbf[t][b][:] . Wx[n][:]   M=65536, N=2048, K=512
__global__ __launch_bounds__(256, 3)
void zx_gemm(const unsigned short* __restrict__ Xbf, const unsigned short* __restrict__ Wx,
             unsigned short* __restrict__ zx)
{
  __shared__ __align__(16) unsigned short As[8192];   // 16 KB, 1024 granules (swizzled)
  __shared__ __align__(16) unsigned short Bs[8192];
  __shared__ float Zs[64][68];

  const int tid  = threadIdx.x;
  const int lane = tid & 63;
  const int w    = tid >> 6;
  const int llo  = lane & 15;
  const int lhi  = lane >> 4;
  const int wm   = (w >> 1) & 1;
  const int wn   = w & 1;

  const int n0 = blockIdx.x << 6;              // 0..2047 step 64
  const int by = blockIdx.y;                   // 0..1023
  const int t  = by >> 4;
  const int b0 = (by & 15) << 6;

  facc4 acc00 = {0.f,0.f,0.f,0.f};
  facc4 acc01 = acc00, acc10 = acc00, acc11 = acc00;

  const int am0 = (wm << 5) + llo;
  const int bn0 = (wn << 5) + llo;

  for (int ci = 0; ci < 4; ++ci) {
    const int kb = ci << 7;
#pragma unroll
    for (int j = 0; j < 4; ++j) {
      int p = (j << 8) + tid;
      int r = p >> 4, ps = p & 15;
      int s = (ps & 8) | ((ps ^ r) & 7);
      gl2lds16(Xbf + ((((size_t)t << 10) + (b0 + r)) << 9) + kb + (s << 3), &As[p << 3]);
      gl2lds16(Wx  + (((size_t)(n0 + r)) << 9) + kb + (s << 3),             &Bs[p << 3]);
    }
    __syncthreads();
#pragma unroll
    for (int kk = 0; kk < 4; ++kk) {
      const int s0 = (kk << 2) + lhi;
      bfrag8 a0 = *(const bfrag8*)&As[foff(am0,      s0)];
      bfrag8 a1 = *(const bfrag8*)&As[foff(am0 + 16, s0)];
      bfrag8 b0 = *(const bfrag8*)&Bs[foff(bn0,      s0)];
      bfrag8 b1 = *(const bfrag8*)&Bs[foff(bn0 + 16, s0)];
      acc00 = MFMA_B16(a0, b0, acc00);
      acc01 = MFMA_B16(a0, b1, acc01);
      acc10 = MFMA_B16(a1, b0, acc10);
      acc11 = MFMA_B16(a1, b1, acc11);
    }
    __syncthreads();
  }

  // spill: C/D layout col=lane&15, row=(lane>>4)*4+reg
#pragma unroll
  for (int rr = 0; rr < 4; ++rr) {
    int rbase = (wm << 5) + (lhi << 2) + rr;
    int cbase = (wn << 5) + llo;
    Zs[rbase][cbase]           = acc00[rr];
    Zs[rbase][cbase + 16]      = acc01[rr];
    Zs[rbase + 16][cbase]      = acc10[rr];
    Zs[rbase + 16][cbase + 16] = acc11[rr];
  }
  __syncthreads();

  const int hs = tid & 15;
  const int rw = tid >> 4;
#pragma unroll
  for (int it = 0; it < 4; ++it) {
    int row = rw + (it << 4);
    float4 z = *(const float4*)&Zs[row][hs << 2];
    ushort4 o;
    o.x = __half_as_ushort(__float2half(z.x));
    o.y = __half_as_ushort(__float2half(z.y));
    o.z = __half_as_ushort(__float2half(z.z));
    o.w = __half_as_ushort(__float2half(z.w));
    *(ushort4*)&zx[((((size_t)t << 10) + (b0 + row)) << 11) + n0 + (hs << 2)] = o;
  }
}

// ---------------- persistent recurrence ----------------
// Plain launch, 512 blocks = 16 m-blocks x 32 n-blocks, 64 steps, manual grid barrier.
// Per step: z = zx[t] + h_{t-1} @ Wh^T ; gates; c (registers), h -> Hbuf ping-pong.
__global__ __launch_bounds__(256, 2)
void lstm_persist(unsigned short* __restrict__ Hbuf,      // [2][1024][512] bf16
                  const unsigned short* __restrict__ Wh,  // [2048][512] bf16
                  const unsigned short* __restrict__ zx,  // [64][1024][2048] fp16
                  const float* __restrict__ biasr,
                  float* __restrict__ out,                // [1024][64][512]
                  unsigned int* __restrict__ bar)         // [64] barrier counters
{
  // Zs only live after the GEMM phase (fenced by __syncthreads both sides) -> union
  // with As/Bs. 33 KB/block => LDS can't break 2 blocks/CU co-residency.
  __shared__ __align__(16) union SmemU {
    struct { unsigned short As[8192]; unsigned short Bs[8192]; } ab;
    float Zs[64][68];
  } smem;
  unsigned short* As = smem.ab.As;
  unsigned short* Bs = smem.ab.Bs;

  const int tid  = threadIdx.x;
  const int lane = tid & 63;
  const int w    = tid >> 6;
  const int llo  = lane & 15;
  const int lhi  = lane >> 4;
  const int wm   = (w >> 1) & 1;
  const int wn   = w & 1;

  const int bx = blockIdx.x;
  const int nb = bx & 31;                      // n-block 0..31
  const int n0 = nb << 6;
  const int m0 = (bx >> 5) << 6;               // m-block 0..15

  const int hs = tid & 15;
  const int rw = tid >> 4;
  const int hglob = (nb << 4) + hs;

  const int am0 = (wm << 5) + llo;
  const int bn0 = (wn << 5) + llo;

  const float4 bb = *(const float4*)&biasr[(size_t)hglob << 2];
  float c[4] = {0.f, 0.f, 0.f, 0.f};

  const size_t HSZ = (size_t)1024 * 512;

  for (int t = 0; t < 64; ++t) {
    if (t) grid_barrier(bar, t - 1);           // all blocks finished step t-1

    const unsigned short* Hprev = Hbuf + (size_t)(t & 1) * HSZ;
    unsigned short*       Hnext = Hbuf + (size_t)((t + 1) & 1) * HSZ;
    const unsigned short* zxt   = zx + ((size_t)t << 21);

    // Prefetch epilogue operands (latency hidden under the GEMM).
    ushort4 zp[4];
#pragma unroll
    for (int it = 0; it < 4; ++it) {
      int b = m0 + rw + (it << 4);
      zp[it] = *(const ushort4*)&zxt[((size_t)b << 11) + n0 + (hs << 2)];
    }

    facc4 acc00 = {0.f,0.f,0.f,0.f};
    facc4 acc01 = acc00, acc10 = acc00, acc11 = acc00;

    if (t) {
      for (int ci = 0; ci < 4; ++ci) {
        const int kb = ci << 7;
#pragma unroll
        for (int j = 0; j < 4; ++j) {
          int p = (j << 8) + tid;
          int r = p >> 4, ps = p & 15;
          int s = (ps & 8) | ((ps ^ r) & 7);
          gl2lds16(Hprev + (((size_t)(m0 + r)) << 9) + kb + (s << 3), &As[p << 3]);
          gl2lds16(Wh    + (((size_t)(n0 + r)) << 9) + kb + (s << 3), &Bs[p << 3]);
        }
        __syncthreads();
#pragma unroll
        for (int kk = 0; kk < 4; ++kk) {
          const int s0 = (kk << 2) + lhi;
          bfrag8 a0 = *(const bfrag8*)&As[foff(am0,      s0)];
          bfrag8 a1 = *(const bfrag8*)&As[foff(am0 + 16, s0)];
          bfrag8 b0 = *(const bfrag8*)&Bs[foff(bn0,      s0)];
          bfrag8 b1 = *(const bfrag8*)&Bs[foff(bn0 + 16, s0)];
          acc00 = MFMA_B16(a0, b0, acc00);
          acc01 = MFMA_B16(a0, b1, acc01);
          acc10 = MFMA_B16(a1, b0, acc10);
          acc11 = MFMA_B16(a1, b1, acc11);
        }
        __syncthreads();
      }
    }

    // spill: C/D layout col=lane&15, row=(lane>>4)*4+reg
#pragma unroll
    for (int rr = 0; rr < 4; ++rr) {
      int rbase = (wm << 5) + (lhi << 2) + rr;
      int cbase = (wn << 5) + llo;
      smem.Zs[rbase][cbase]           = acc00[rr];
      smem.Zs[rbase][cbase + 16]      = acc01[rr];
      smem.Zs[rbase + 16][cbase]      = acc10[rr];
      smem.Zs[rbase + 16][cbase + 16] = acc11[rr];
    }
    __syncthreads();

    // epilogue: z = Zs + zx + bias; gates; c in regs; h -> Hnext + out
#pragma unroll
    for (int it = 0; it < 4; ++it) {
      int row = rw + (it << 4);
      int b   = m0 + row;
      float4 z = *(const float4*)&smem.Zs[row][hs << 2];
      float zi = z.x + __half2float(__ushort_as_half(zp[it].x)) + bb.x;
      float zf = z.y + __half2float(__ushort_as_half(zp[it].y)) + bb.y;
      float zg = z.z + __half2float(__ushort_as_half(zp[it].z)) + bb.z;
      float zo = z.w + __half2float(__ushort_as_half(zp[it].w)) + bb.w;
      float ig = sigm(zi);
      float fg = sigm(zf);
      float gg = tanh_(zg);
      float og = sigm(zo);
      float cn = fg * c[it] + ig * gg;
      c[it] = cn;
      float hn = og * tanh_(cn);
      size_t idx = ((size_t)b << 9) + hglob;
      Hnext[idx] = f2bf(hn);
      out[((size_t)b << 15) + ((size_t)t << 9) + hglob] = hn;
    }
    __syncthreads();   // Zs (aliases As/Bs) reuse hazard vs next step's staging
  }
}

extern "C" void kernel_launch(void* const* d_in, const int* in_sizes, int n_in,
                              void* d_out, int out_size, void* d_ws, size_t ws_size,
                              hipStream_t stream) {
  const float* x    = (const float*)d_in[0];   // [1024][64][512]
  const float* Wk   = (const float*)d_in[1];   // [512][2048]
  const float* Wr   = (const float*)d_in[2];   // [512][2048]
  const float* bias = (const float*)d_in[3];   // [2048]
  float* out = (float*)d_out;                  // [1024][64][512]

  char* ws = (char*)d_ws;
  // ws (16B-aligned): Wx 2MiB | Wh 2MiB | biasr 8KB | Hbuf 2x1MiB | bar 256B | Xbf 64MiB | zx 256MiB
  unsigned short* Wx    = (unsigned short*)(ws);
  unsigned short* Wh    = (unsigned short*)(ws + (2u << 20));
  float*          biasr = (float*)(ws + (4u << 20));
  unsigned short* Hbuf  = (unsigned short*)(ws + (4u << 20) + 8192);
  unsigned int*   bar   = (unsigned int*)(ws + (6u << 20) + 8192);
  unsigned short* Xbf   = (unsigned short*)(ws + (8u << 20) + 8192);
  unsigned short* zx    = (unsigned short*)(ws + (72u << 20) + 8192);

  prep_w<<<dim3(8192), dim3(256), 0, stream>>>(Wk, Wr, bias, Wx, Wh, biasr, bar);
  prep_x<<<dim3(16384), dim3(256), 0, stream>>>(x, Xbf);
  zx_gemm<<<dim3(32, 1024), dim3(256), 0, stream>>>(Xbf, Wx, zx);
  lstm_persist<<<dim3(512), dim3(256), 0, stream>>>(Hbuf, Wh, zx, biasr, out, bar);
}

// Round 4
// 2541.884 us; speedup vs baseline: 1.5584x; 1.5584x over previous
//
#include <hip/hip_runtime.h>
#include <hip/hip_bf16.h>
#include <hip/hip_fp16.h>

// LSTM, T=64. Structure:
//   prep_w : Wx[2048][512], Wh[2048][512] bf16 (gate-interleaved n=4h+g, K-transposed), biasr.
//            Also zeroes the 1024 per-(step,m-group) barrier counters.
//   prep_x : Xbf[t][b][512] bf16 (time-major).
//   zx_gemm: zx[t][b][2048] = Xbf @ Wx^T, fp16 storage (parallel, off the critical path).
//   lstm_persist: ONE plain-launched persistent kernel, 512 blocks (16 m x 32 n, 2/CU),
//            64 steps. Synchronization is PER-M-GROUP (32 blocks share batch rows m0..m0+63;
//            only they exchange h), via a per-step counter. NO cache-wide fences:
//            h crosses blocks through coherent (sc0 sc1) stores/loads only, so Wh stays
//            L2-resident across steps and no buffer_wbl2/buffer_inv walks are issued.
//            c-state register-resident; h ping-pongs in Hbuf[0/1].
// LDS staging: B (Wh) via global_load_lds width=16 with XOR-swizzled SOURCE permutation;
// A (Hprev) reg-staged with coherent asm loads + ds_write_b128 to the same swizzled layout
// (phys granule = (seg&8)|((seg^row)&7)) so unpadded frag reads are bank-optimal.
// lstm_persist LDS: Zs unioned with As/Bs (33 KB/block) to guarantee 2 blocks/CU residency.

typedef __attribute__((ext_vector_type(8))) short bfrag8;
typedef __attribute__((ext_vector_type(4))) float facc4;

#define MFMA_B16(a, b, c) __builtin_amdgcn_mfma_f32_16x16x32_bf16(a, b, c, 0, 0, 0)

#define GRP 32u   // blocks per m-group barrier

__device__ __forceinline__ unsigned short f2bf(float f) {
  unsigned int u = __float_as_uint(f);
  u += 0x7FFFu + ((u >> 16) & 1u);          // RNE
  return (unsigned short)(u >> 16);
}
__device__ __forceinline__ float sigm(float x)  { return 1.0f / (1.0f + __expf(-x)); }
__device__ __forceinline__ float tanh_(float x) { return 1.0f - 2.0f / (__expf(2.0f * x) + 1.0f); }

__device__ __forceinline__ void gl2lds16(const void* g, void* l) {
  __builtin_amdgcn_global_load_lds(
      (const __attribute__((address_space(1))) unsigned int*)g,
      (__attribute__((address_space(3))) unsigned int*)l, 16, 0, 0);
}

// Coherent 16B load (bypasses stale L1/L2, reads device-coherent point).
__device__ __forceinline__ uint4 ld128_coh(const void* p) {
  uint4 r;
  asm volatile("global_load_dwordx4 %0, %1, off sc0 sc1" : "=v"(r) : "v"(p));
  return r;
}
// Coherent 2B store (write-through to device-coherent point).
__device__ __forceinline__ void st16_coh(void* p, unsigned short v) {
  asm volatile("global_store_short %0, %1, off sc0 sc1" :: "v"(p), "v"(v));
}

// ushort offset of logical granule (row, seg) in a [64 rows][16 segs] swizzled tile.
__device__ __forceinline__ int foff(int row, int seg) {
  return (row << 7) + ((((seg & 8) | ((seg ^ row) & 7))) << 3);
}

// Per-m-group barrier (32 blocks), one counter slot per (step, group). No fences:
// h traffic is coherent by construction (sc0 sc1); vmcnt(0) = own stores at coherent point.
__device__ __forceinline__ void group_barrier(unsigned int* bar, int slot) {
  asm volatile("s_waitcnt vmcnt(0)" ::: "memory");   // own h-stores visible device-wide
  __syncthreads();                                   // whole block done with step
  if (threadIdx.x == 0) {
    __hip_atomic_fetch_add(&bar[slot], 1u, __ATOMIC_RELAXED, __HIP_MEMORY_SCOPE_AGENT);
    while (__hip_atomic_load(&bar[slot], __ATOMIC_RELAXED, __HIP_MEMORY_SCOPE_AGENT) < GRP)
      __builtin_amdgcn_s_sleep(2);
  }
  __syncthreads();
}

// ---------------- prep kernels ----------------

__global__ void prep_w(const float* __restrict__ Wk, const float* __restrict__ Wr,
                       const float* __restrict__ bias,
                       unsigned short* __restrict__ Wx, unsigned short* __restrict__ Wh,
                       float* __restrict__ biasr, unsigned int* __restrict__ bar)
{
  int gid = (blockIdx.x << 8) + threadIdx.x;   // 0 .. 2M-1
  int k   = gid >> 11;                         // 0..1023
  int col = gid & 2047;                        // original column g*512+h
  float v = (k < 512) ? Wk[((size_t)k << 11) + col]
                      : Wr[((size_t)(k - 512) << 11) + col];
  int n = ((col & 511) << 2) | (col >> 9);     // 4h+g
  if (k < 512) Wx[((size_t)n << 9) + k]         = f2bf(v);
  else         Wh[((size_t)n << 9) + (k - 512)] = f2bf(v);
  if (gid < 2048) biasr[((gid & 511) << 2) | (gid >> 9)] = bias[gid];
  if (gid < 1024) bar[gid] = 0u;               // zero barrier counters each run
}

__global__ void prep_x(const float* __restrict__ x, unsigned short* __restrict__ Xbf)
{
  int flat = (blockIdx.x << 8) + threadIdx.x;  // 0 .. 4,194,303 (granules of 8)
  int d8 = flat & 63;
  int b  = (flat >> 6) & 1023;
  int t  = flat >> 16;
  const float* src = x + ((((size_t)b << 6) + t) << 9) + (d8 << 3);
  float4 v0 = *(const float4*)src;
  float4 v1 = *(const float4*)(src + 4);
  uint4 u;
  u.x = f2bf(v0.x) | ((unsigned)f2bf(v0.y) << 16);
  u.y = f2bf(v0.z) | ((unsigned)f2bf(v0.w) << 16);
  u.z = f2bf(v1.x) | ((unsigned)f2bf(v1.y) << 16);
  u.w = f2bf(v1.z) | ((unsigned)f2bf(v1.w) << 16);
  *(uint4*)&Xbf[((((size_t)t << 10) + b) << 9) + (d8 << 3)] = u;
}

// ---------------- zx precompute GEMM ----------------
// zx[t][b][n] (fp16) = Xbf[t][b][:] . Wx[n][:]   M=65536, N=2048, K=512
__global__ __launch_bounds__(256, 3)
void zx_gemm(const unsigned short* __restrict__ Xbf, const unsigned short* __restrict__ Wx,
             unsigned short* __restrict__ zx)
{
  __shared__ __align__(16) unsigned short As[8192];   // 16 KB, 1024 granules (swizzled)
  __shared__ __align__(16) unsigned short Bs[8192];
  __shared__ float Zs[64][68];

  const int tid  = threadIdx.x;
  const int lane = tid & 63;
  const int w    = tid >> 6;
  const int llo  = lane & 15;
  const int lhi  = lane >> 4;
  const int wm   = (w >> 1) & 1;
  const int wn   = w & 1;

  const int n0 = blockIdx.x << 6;              // 0..2047 step 64
  const int by = blockIdx.y;                   // 0..1023
  const int t  = by >> 4;
  const int b0 = (by & 15) << 6;

  facc4 acc00 = {0.f,0.f,0.f,0.f};
  facc4 acc01 = acc00, acc10 = acc00, acc11 = acc00;

  const int am0 = (wm << 5) + llo;
  const int bn0 = (wn << 5) + llo;

  for (int ci = 0; ci < 4; ++ci) {
    const int kb = ci << 7;
#pragma unroll
    for (int j = 0; j < 4; ++j) {
      int p = (j << 8) + tid;
      int r = p >> 4, ps = p & 15;
      int s = (ps & 8) | ((ps ^ r) & 7);
      gl2lds16(Xbf + ((((size_t)t << 10) + (b0 + r)) << 9) + kb + (s << 3), &As[p << 3]);
      gl2lds16(Wx  + (((size_t)(n0 + r)) << 9) + kb + (s << 3),             &Bs[p << 3]);
    }
    __syncthreads();
#pragma unroll
    for (int kk = 0; kk < 4; ++kk) {
      const int s0 = (kk << 2) + lhi;
      bfrag8 a0 = *(const bfrag8*)&As[foff(am0,      s0)];
      bfrag8 a1 = *(const bfrag8*)&As[foff(am0 + 16, s0)];
      bfrag8 b0 = *(const bfrag8*)&Bs[foff(bn0,      s0)];
      bfrag8 b1 = *(const bfrag8*)&Bs[foff(bn0 + 16, s0)];
      acc00 = MFMA_B16(a0, b0, acc00);
      acc01 = MFMA_B16(a0, b1, acc01);
      acc10 = MFMA_B16(a1, b0, acc10);
      acc11 = MFMA_B16(a1, b1, acc11);
    }
    __syncthreads();
  }

  // spill: C/D layout col=lane&15, row=(lane>>4)*4+reg
#pragma unroll
  for (int rr = 0; rr < 4; ++rr) {
    int rbase = (wm << 5) + (lhi << 2) + rr;
    int cbase = (wn << 5) + llo;
    Zs[rbase][cbase]           = acc00[rr];
    Zs[rbase][cbase + 16]      = acc01[rr];
    Zs[rbase + 16][cbase]      = acc10[rr];
    Zs[rbase + 16][cbase + 16] = acc11[rr];
  }
  __syncthreads();

  const int hs = tid & 15;
  const int rw = tid >> 4;
#pragma unroll
  for (int it = 0; it < 4; ++it) {
    int row = rw + (it << 4);
    float4 z = *(const float4*)&Zs[row][hs << 2];
    ushort4 o;
    o.x = __half_as_ushort(__float2half(z.x));
    o.y = __half_as_ushort(__float2half(z.y));
    o.z = __half_as_ushort(__float2half(z.z));
    o.w = __half_as_ushort(__float2half(z.w));
    *(ushort4*)&zx[((((size_t)t << 10) + (b0 + row)) << 11) + n0 + (hs << 2)] = o;
  }
}

// ---------------- persistent recurrence ----------------
// Plain launch, 512 blocks = 16 m-blocks x 32 n-blocks, 64 steps, per-m-group barriers.
// Per step: z = zx[t] + h_{t-1} @ Wh^T ; gates; c (registers), h -> Hbuf ping-pong.
__global__ __launch_bounds__(256, 2)
void lstm_persist(unsigned short* __restrict__ Hbuf,      // [2][1024][512] bf16
                  const unsigned short* __restrict__ Wh,  // [2048][512] bf16
                  const unsigned short* __restrict__ zx,  // [64][1024][2048] fp16
                  const float* __restrict__ biasr,
                  float* __restrict__ out,                // [1024][64][512]
                  unsigned int* __restrict__ bar)         // [64][16] barrier counters
{
  // Zs only live after the GEMM phase (fenced by __syncthreads both sides) -> union
  // with As/Bs. 33 KB/block => LDS can't break 2 blocks/CU co-residency.
  __shared__ __align__(16) union SmemU {
    struct { unsigned short As[8192]; unsigned short Bs[8192]; } ab;
    float Zs[64][68];
  } smem;
  unsigned short* As = smem.ab.As;
  unsigned short* Bs = smem.ab.Bs;

  const int tid  = threadIdx.x;
  const int lane = tid & 63;
  const int w    = tid >> 6;
  const int llo  = lane & 15;
  const int lhi  = lane >> 4;
  const int wm   = (w >> 1) & 1;
  const int wn   = w & 1;

  const int bx = blockIdx.x;
  const int nb = bx & 31;                      // n-block 0..31
  const int n0 = nb << 6;
  const int mg = bx >> 5;                      // m-group 0..15
  const int m0 = mg << 6;

  const int hs = tid & 15;
  const int rw = tid >> 4;
  const int hglob = (nb << 4) + hs;

  const int am0 = (wm << 5) + llo;
  const int bn0 = (wn << 5) + llo;

  const float4 bb = *(const float4*)&biasr[(size_t)hglob << 2];
  float c[4] = {0.f, 0.f, 0.f, 0.f};

  const size_t HSZ = (size_t)1024 * 512;

  for (int t = 0; t < 64; ++t) {
    const unsigned short* zxt = zx + ((size_t)t << 21);

    // Prefetch epilogue operands BEFORE the barrier (h-independent; latency hides
    // under the barrier's vmcnt drain + spin).
    ushort4 zp[4];
#pragma unroll
    for (int it = 0; it < 4; ++it) {
      int b = m0 + rw + (it << 4);
      zp[it] = *(const ushort4*)&zxt[((size_t)b << 11) + n0 + (hs << 2)];
    }

    if (t) group_barrier(bar, ((t - 1) << 4) + mg);   // group finished step t-1

    const unsigned short* Hprev = Hbuf + (size_t)(t & 1) * HSZ;
    unsigned short*       Hnext = Hbuf + (size_t)((t + 1) & 1) * HSZ;

    facc4 acc00 = {0.f,0.f,0.f,0.f};
    facc4 acc01 = acc00, acc10 = acc00, acc11 = acc00;

    if (t) {
      for (int ci = 0; ci < 4; ++ci) {
        const int kb = ci << 7;
        uint4 av[4];
#pragma unroll
        for (int j = 0; j < 4; ++j) {
          int p = (j << 8) + tid;
          int r = p >> 4, ps = p & 15;
          int s = (ps & 8) | ((ps ^ r) & 7);
          gl2lds16(Wh + (((size_t)(n0 + r)) << 9) + kb + (s << 3), &Bs[p << 3]);
          av[j] = ld128_coh(Hprev + (((size_t)(m0 + r)) << 9) + kb + (s << 3));
        }
        asm volatile("s_waitcnt vmcnt(0)" ::: "memory");   // asm loads done (rule #18)
        __builtin_amdgcn_sched_barrier(0);
#pragma unroll
        for (int j = 0; j < 4; ++j) {
          int p = (j << 8) + tid;
          *(uint4*)&As[p << 3] = av[j];                    // same swizzled layout
        }
        __syncthreads();
#pragma unroll
        for (int kk = 0; kk < 4; ++kk) {
          const int s0 = (kk << 2) + lhi;
          bfrag8 a0 = *(const bfrag8*)&As[foff(am0,      s0)];
          bfrag8 a1 = *(const bfrag8*)&As[foff(am0 + 16, s0)];
          bfrag8 b0 = *(const bfrag8*)&Bs[foff(bn0,      s0)];
          bfrag8 b1 = *(const bfrag8*)&Bs[foff(bn0 + 16, s0)];
          acc00 = MFMA_B16(a0, b0, acc00);
          acc01 = MFMA_B16(a0, b1, acc01);
          acc10 = MFMA_B16(a1, b0, acc10);
          acc11 = MFMA_B16(a1, b1, acc11);
        }
        __syncthreads();
      }
    }

    // spill: C/D layout col=lane&15, row=(lane>>4)*4+reg
#pragma unroll
    for (int rr = 0; rr < 4; ++rr) {
      int rbase = (wm << 5) + (lhi << 2) + rr;
      int cbase = (wn << 5) + llo;
      smem.Zs[rbase][cbase]           = acc00[rr];
      smem.Zs[rbase][cbase + 16]      = acc01[rr];
      smem.Zs[rbase + 16][cbase]      = acc10[rr];
      smem.Zs[rbase + 16][cbase + 16] = acc11[rr];
    }
    __syncthreads();

    // epilogue: z = Zs + zx + bias; gates; c in regs; h -> Hnext (coherent) + out
#pragma unroll
    for (int it = 0; it < 4; ++it) {
      int row = rw + (it << 4);
      int b   = m0 + row;
      float4 z = *(const float4*)&smem.Zs[row][hs << 2];
      float zi = z.x + __half2float(__ushort_as_half(zp[it].x)) + bb.x;
      float zf = z.y + __half2float(__ushort_as_half(zp[it].y)) + bb.y;
      float zg = z.z + __half2float(__ushort_as_half(zp[it].z)) + bb.z;
      float zo = z.w + __half2float(__ushort_as_half(zp[it].w)) + bb.w;
      float ig = sigm(zi);
      float fg = sigm(zf);
      float gg = tanh_(zg);
      float og = sigm(zo);
      float cn = fg * c[it] + ig * gg;
      c[it] = cn;
      float hn = og * tanh_(cn);
      size_t idx = ((size_t)b << 9) + hglob;
      st16_coh(&Hnext[idx], f2bf(hn));
      out[((size_t)b << 15) + ((size_t)t << 9) + hglob] = hn;
    }
    // Zs-vs-As reuse hazard is covered by next iteration's group_barrier entry
    // __syncthreads (staging only happens after it).
  }
}

extern "C" void kernel_launch(void* const* d_in, const int* in_sizes, int n_in,
                              void* d_out, int out_size, void* d_ws, size_t ws_size,
                              hipStream_t stream) {
  const float* x    = (const float*)d_in[0];   // [1024][64][512]
  const float* Wk   = (const float*)d_in[1];   // [512][2048]
  const float* Wr   = (const float*)d_in[2];   // [512][2048]
  const float* bias = (const float*)d_in[3];   // [2048]
  float* out = (float*)d_out;                  // [1024][64][512]

  char* ws = (char*)d_ws;
  // ws (16B-aligned): Wx 2MiB | Wh 2MiB | biasr 8KB | Hbuf 2x1MiB | bar 4KB | Xbf 64MiB | zx 256MiB
  unsigned short* Wx    = (unsigned short*)(ws);
  unsigned short* Wh    = (unsigned short*)(ws + (2u << 20));
  float*          biasr = (float*)(ws + (4u << 20));
  unsigned short* Hbuf  = (unsigned short*)(ws + (4u << 20) + 8192);
  unsigned int*   bar   = (unsigned int*)(ws + (6u << 20) + 8192);
  unsigned short* Xbf   = (unsigned short*)(ws + (8u << 20) + 8192);
  unsigned short* zx    = (unsigned short*)(ws + (72u << 20) + 8192);

  prep_w<<<dim3(8192), dim3(256), 0, stream>>>(Wk, Wr, bias, Wx, Wh, biasr, bar);
  prep_x<<<dim3(16384), dim3(256), 0, stream>>>(x, Xbf);
  zx_gemm<<<dim3(32, 1024), dim3(256), 0, stream>>>(Xbf, Wx, zx);
  lstm_persist<<<dim3(512), dim3(256), 0, stream>>>(Hbuf, Wh, zx, biasr, out, bar);
}

// Round 7
// 1368.956 us; speedup vs baseline: 2.8937x; 1.8568x over previous
//
#include <hip/hip_runtime.h>
#include <hip/hip_bf16.h>
#include <hip/hip_fp16.h>

// LSTM, T=64. Structure:
//   prep_w : Wx[2048][512], Wh[2048][512] bf16 (gate-interleaved n=4h+g, K-transposed), biasr.
//            Also zeroes the 1024 per-(step,m-group) barrier counters.
//   prep_x : Xbf[t][b][512] bf16 (time-major).
//   zx_gemm: zx[t][b][2048] = Xbf @ Wx^T, fp16 storage (parallel, off the critical path).
//   lstm_persist v3: 256 blocks = 16 m-groups (64 batch rows) x 16 n-slices (128 gate cols),
//            1 block/CU (148 KB dynamic LDS), 64 steps, per-m-group barriers (16 blocks).
//            Wh n-slice LDS-RESIDENT for all 64 steps (no per-step Wh traffic at all).
//            Swapped-operand MFMA: D[n][b] = Wh_frag x h_frag, so each lane's facc4 is
//            (zi,zf,zg,zo) for one (h,b) -> fully in-register epilogue, no LDS transpose.
//            h-exchange: single-shot 16x dwordx4 sc0+sc1 coherent loads (counted vmcnt),
//            stores repacked through LDS scratch into one 16B coherent store per b-row strip.
//            c-state register-resident; h ping-pongs in Hbuf[0/1]. No cache-wide fences.
// LDS swizzle: phys granule = (seg&8)|((seg^row)&7) so unpadded frag reads are bank-optimal.

typedef __attribute__((ext_vector_type(8))) short bfrag8;
typedef __attribute__((ext_vector_type(4))) float facc4;
typedef __attribute__((ext_vector_type(4))) unsigned int u32x4;  // asm-friendly 128b

#define MFMA_B16(a, b, c) __builtin_amdgcn_mfma_f32_16x16x32_bf16(a, b, c, 0, 0, 0)

#define GRP 16u   // blocks per m-group barrier

__device__ __forceinline__ unsigned short f2bf(float f) {
  unsigned int u = __float_as_uint(f);
  u += 0x7FFFu + ((u >> 16) & 1u);          // RNE
  return (unsigned short)(u >> 16);
}
__device__ __forceinline__ float sigm(float x)  { return 1.0f / (1.0f + __expf(-x)); }
__device__ __forceinline__ float tanh_(float x) { return 1.0f - 2.0f / (__expf(2.0f * x) + 1.0f); }

__device__ __forceinline__ void gl2lds16(const void* g, void* l) {
  __builtin_amdgcn_global_load_lds(
      (const __attribute__((address_space(1))) unsigned int*)g,
      (__attribute__((address_space(3))) unsigned int*)l, 16, 0, 0);
}

// Coherent 16B load/store (bypass stale L1/L2, device-coherent point).
// NOTE: asm operands must be ext_vector types (struct uint4 inputs are rejected:
// "indirect register inputs" — R6 compile failure).
__device__ __forceinline__ u32x4 ld128_coh(const void* p) {
  u32x4 r;
  asm volatile("global_load_dwordx4 %0, %1, off sc0 sc1" : "=v"(r) : "v"(p));
  return r;
}
__device__ __forceinline__ void st128_coh(void* p, u32x4 v) {
  asm volatile("global_store_dwordx4 %0, %1, off sc0 sc1" :: "v"(p), "v"(v));
}

// ushort offset of logical granule (row, seg) in a [rows][16 segs] swizzled tile.
__device__ __forceinline__ int foff(int row, int seg) {
  return (row << 7) + ((((seg & 8) | ((seg ^ row) & 7))) << 3);
}

// Per-m-group barrier (16 blocks), one counter slot per (step, group). No fences:
// h traffic is coherent by construction (sc0 sc1); vmcnt(0) = own stores at coherent point.
__device__ __forceinline__ void group_barrier(unsigned int* bar, int slot) {
  asm volatile("s_waitcnt vmcnt(0)" ::: "memory");   // own h-stores visible device-wide
  __syncthreads();                                   // whole block done with step
  if (threadIdx.x == 0) {
    __hip_atomic_fetch_add(&bar[slot], 1u, __ATOMIC_RELAXED, __HIP_MEMORY_SCOPE_AGENT);
    while (__hip_atomic_load(&bar[slot], __ATOMIC_RELAXED, __HIP_MEMORY_SCOPE_AGENT) < GRP)
      __builtin_amdgcn_s_sleep(2);
  }
  __syncthreads();
}

// ---------------- prep kernels ----------------

__global__ void prep_w(const float* __restrict__ Wk, const float* __restrict__ Wr,
                       const float* __restrict__ bias,
                       unsigned short* __restrict__ Wx, unsigned short* __restrict__ Wh,
                       float* __restrict__ biasr, unsigned int* __restrict__ bar)
{
  int gid = (blockIdx.x << 8) + threadIdx.x;   // 0 .. 2M-1
  int k   = gid >> 11;                         // 0..1023
  int col = gid & 2047;                        // original column g*512+h
  float v = (k < 512) ? Wk[((size_t)k << 11) + col]
                      : Wr[((size_t)(k - 512) << 11) + col];
  int n = ((col & 511) << 2) | (col >> 9);     // 4h+g
  if (k < 512) Wx[((size_t)n << 9) + k]         = f2bf(v);
  else         Wh[((size_t)n << 9) + (k - 512)] = f2bf(v);
  if (gid < 2048) biasr[((gid & 511) << 2) | (gid >> 9)] = bias[gid];
  if (gid < 1024) bar[gid] = 0u;               // zero barrier counters each run
}

__global__ void prep_x(const float* __restrict__ x, unsigned short* __restrict__ Xbf)
{
  int flat = (blockIdx.x << 8) + threadIdx.x;  // 0 .. 4,194,303 (granules of 8)
  int d8 = flat & 63;
  int b  = (flat >> 6) & 1023;
  int t  = flat >> 16;
  const float* src = x + ((((size_t)b << 6) + t) << 9) + (d8 << 3);
  float4 v0 = *(const float4*)src;
  float4 v1 = *(const float4*)(src + 4);
  uint4 u;
  u.x = f2bf(v0.x) | ((unsigned)f2bf(v0.y) << 16);
  u.y = f2bf(v0.z) | ((unsigned)f2bf(v0.w) << 16);
  u.z = f2bf(v1.x) | ((unsigned)f2bf(v1.y) << 16);
  u.w = f2bf(v1.z) | ((unsigned)f2bf(v1.w) << 16);
  *(uint4*)&Xbf[((((size_t)t << 10) + b) << 9) + (d8 << 3)] = u;
}

// ---------------- zx precompute GEMM ----------------
// zx[t][b][n] (fp16) = Xbf[t][b][:] . Wx[n][:]   M=65536, N=2048, K=512
__global__ __launch_bounds__(256, 3)
void zx_gemm(const unsigned short* __restrict__ Xbf, const unsigned short* __restrict__ Wx,
             unsigned short* __restrict__ zx)
{
  __shared__ __align__(16) unsigned short As[8192];   // 16 KB, 1024 granules (swizzled)
  __shared__ __align__(16) unsigned short Bs[8192];
  __shared__ float Zs[64][68];

  const int tid  = threadIdx.x;
  const int lane = tid & 63;
  const int w    = tid >> 6;
  const int llo  = lane & 15;
  const int lhi  = lane >> 4;
  const int wm   = (w >> 1) & 1;
  const int wn   = w & 1;

  const int n0 = blockIdx.x << 6;              // 0..2047 step 64
  const int by = blockIdx.y;                   // 0..1023
  const int t  = by >> 4;
  const int b0 = (by & 15) << 6;

  facc4 acc00 = {0.f,0.f,0.f,0.f};
  facc4 acc01 = acc00, acc10 = acc00, acc11 = acc00;

  const int am0 = (wm << 5) + llo;
  const int bn0 = (wn << 5) + llo;

  for (int ci = 0; ci < 4; ++ci) {
    const int kb = ci << 7;
#pragma unroll
    for (int j = 0; j < 4; ++j) {
      int p = (j << 8) + tid;
      int r = p >> 4, ps = p & 15;
      int s = (ps & 8) | ((ps ^ r) & 7);
      gl2lds16(Xbf + ((((size_t)t << 10) + (b0 + r)) << 9) + kb + (s << 3), &As[p << 3]);
      gl2lds16(Wx  + (((size_t)(n0 + r)) << 9) + kb + (s << 3),             &Bs[p << 3]);
    }
    __syncthreads();
#pragma unroll
    for (int kk = 0; kk < 4; ++kk) {
      const int s0 = (kk << 2) + lhi;
      bfrag8 a0 = *(const bfrag8*)&As[foff(am0,      s0)];
      bfrag8 a1 = *(const bfrag8*)&As[foff(am0 + 16, s0)];
      bfrag8 b0 = *(const bfrag8*)&Bs[foff(bn0,      s0)];
      bfrag8 b1 = *(const bfrag8*)&Bs[foff(bn0 + 16, s0)];
      acc00 = MFMA_B16(a0, b0, acc00);
      acc01 = MFMA_B16(a0, b1, acc01);
      acc10 = MFMA_B16(a1, b0, acc10);
      acc11 = MFMA_B16(a1, b1, acc11);
    }
    __syncthreads();
  }

  // spill: C/D layout col=lane&15, row=(lane>>4)*4+reg
#pragma unroll
  for (int rr = 0; rr < 4; ++rr) {
    int rbase = (wm << 5) + (lhi << 2) + rr;
    int cbase = (wn << 5) + llo;
    Zs[rbase][cbase]           = acc00[rr];
    Zs[rbase][cbase + 16]      = acc01[rr];
    Zs[rbase + 16][cbase]      = acc10[rr];
    Zs[rbase + 16][cbase + 16] = acc11[rr];
  }
  __syncthreads();

  const int hs = tid & 15;
  const int rw = tid >> 4;
#pragma unroll
  for (int it = 0; it < 4; ++it) {
    int row = rw + (it << 4);
    float4 z = *(const float4*)&Zs[row][hs << 2];
    ushort4 o;
    o.x = __half_as_ushort(__float2half(z.x));
    o.y = __half_as_ushort(__float2half(z.y));
    o.z = __half_as_ushort(__float2half(z.z));
    o.w = __half_as_ushort(__float2half(z.w));
    *(ushort4*)&zx[((((size_t)t << 10) + (b0 + row)) << 11) + n0 + (hs << 2)] = o;
  }
}

// ---------------- persistent recurrence v3 ----------------
// 256 blocks = 16 mg (64 rows) x 16 nb (128 gate cols = 32 h), 256 thr, 1 block/CU.
// LDS (dynamic 148 KB): Bs = Wh slice [4 chunks][128 n][128 k] swizzled, RESIDENT;
//                       As = h chunk [64 b][128 k] swizzled; Sc = 4 KB h-repack scratch.
__global__ __launch_bounds__(256, 1)
void lstm_persist(unsigned short* __restrict__ Hbuf,      // [2][1024][512] bf16
                  const unsigned short* __restrict__ Wh,  // [2048][512] bf16
                  const unsigned short* __restrict__ zx,  // [64][1024][2048] fp16
                  const float* __restrict__ biasr,
                  float* __restrict__ out,                // [1024][64][512]
                  unsigned int* __restrict__ bar)         // [64][16] barrier counters
{
  extern __shared__ __align__(16) char smem_raw[];
  unsigned short* Bs = (unsigned short*)smem_raw;             // 128 KB
  unsigned short* As = (unsigned short*)(smem_raw + 131072);  // 16 KB
  unsigned short* Sc = (unsigned short*)(smem_raw + 147456);  // 4 KB

  const int tid  = threadIdx.x;
  const int lane = tid & 63;
  const int w    = tid >> 6;        // wave 0..3
  const int llo  = lane & 15;
  const int lhi  = lane >> 4;

  const int bx  = blockIdx.x;
  const int nbI = bx & 15;          // n-slice 0..15
  const int mg  = bx >> 4;          // m-group 0..15
  const int m0  = mg << 6;          // batch-row base
  const int n0  = nbI << 7;         // gate-col base (128 cols)
  const int hb  = nbI << 5;         // h base (32 h)

  // ---- prologue: stage resident Wh slice [n0..n0+128) x [0..512) into Bs ----
  for (int i = 0; i < 32; ++i) {
    int p  = (i << 8) + tid;        // 0..8191 granules of 16B
    int ci = p >> 11;               // K-chunk 0..3
    int q  = p & 2047;
    int r  = q >> 4, ps = q & 15;   // n-row 0..127, seg
    int s  = (ps & 8) | ((ps ^ r) & 7);
    gl2lds16(Wh + (((size_t)(n0 + r)) << 9) + (ci << 7) + (s << 3), Bs + ((size_t)p << 3));
  }

  const int nw0 = w << 5;           // wave's n-strip base within 128
  // bias (t-invariant): bb[nt] = biasr[4h .. 4h+3] for h = hb + w*8 + nt*4 + lhi
  float4 bb[2];
  bb[0] = *(const float4*)&biasr[(size_t)(hb + (w << 3) + 0 + lhi) << 2];
  bb[1] = *(const float4*)&biasr[(size_t)(hb + (w << 3) + 4 + lhi) << 2];

  float c[2][4] = {{0.f,0.f,0.f,0.f},{0.f,0.f,0.f,0.f}};

  asm volatile("s_waitcnt vmcnt(0)" ::: "memory");   // Bs staged
  __syncthreads();

  const size_t HSZ = (size_t)1024 * 512;

  for (int t = 0; t < 64; ++t) {
    const unsigned short* zxt = zx + ((size_t)t << 21);

    // zx prefetch (h-independent; hides under barrier drain + spin)
    ushort4 zp[2][4];
#pragma unroll
    for (int nt = 0; nt < 2; ++nt)
#pragma unroll
      for (int bt = 0; bt < 4; ++bt) {
        int b = m0 + (bt << 4) + llo;
        int h = hb + (w << 3) + (nt << 2) + lhi;
        zp[nt][bt] = *(const ushort4*)&zxt[((size_t)b << 11) + (h << 2)];
      }

    if (t) group_barrier(bar, ((t - 1) << 4) + mg);   // group finished step t-1

    const unsigned short* Hprev = Hbuf + (size_t)(t & 1) * HSZ;

    facc4 acc[2][4];
#pragma unroll
    for (int nt = 0; nt < 2; ++nt)
#pragma unroll
      for (int bt = 0; bt < 4; ++bt)
        acc[nt][bt] = (facc4){0.f, 0.f, 0.f, 0.f};

    if (t) {
      // single-shot coherent h load: 16 x dwordx4 (64 KB/block), counted vmcnt
      u32x4 av[16];
#pragma unroll
      for (int ci = 0; ci < 4; ++ci)
#pragma unroll
        for (int j = 0; j < 4; ++j) {
          int p = (j << 8) + tid;
          int r = p >> 4, ps = p & 15;
          int s = (ps & 8) | ((ps ^ r) & 7);
          av[(ci << 2) + j] = ld128_coh(Hprev + (((size_t)(m0 + r)) << 9) + (ci << 7) + (s << 3));
        }
#pragma unroll
      for (int ci = 0; ci < 4; ++ci) {
        if      (ci == 0) asm volatile("s_waitcnt vmcnt(12)" ::: "memory");
        else if (ci == 1) asm volatile("s_waitcnt vmcnt(8)"  ::: "memory");
        else if (ci == 2) asm volatile("s_waitcnt vmcnt(4)"  ::: "memory");
        else              asm volatile("s_waitcnt vmcnt(0)"  ::: "memory");
        __builtin_amdgcn_sched_barrier(0);
#pragma unroll
        for (int j = 0; j < 4; ++j) {
          int p = (j << 8) + tid;
          *(u32x4*)&As[(size_t)p << 3] = av[(ci << 2) + j];
        }
        __syncthreads();
#pragma unroll
        for (int kk = 0; kk < 4; ++kk) {
          const int s0 = (kk << 2) + lhi;
          bfrag8 wh0 = *(const bfrag8*)&Bs[(ci << 14) + foff(nw0 + llo,      s0)];
          bfrag8 wh1 = *(const bfrag8*)&Bs[(ci << 14) + foff(nw0 + 16 + llo, s0)];
#pragma unroll
          for (int bt = 0; bt < 4; ++bt) {
            bfrag8 hf = *(const bfrag8*)&As[foff((bt << 4) + llo, s0)];
            acc[0][bt] = MFMA_B16(wh0, hf, acc[0][bt]);
            acc[1][bt] = MFMA_B16(wh1, hf, acc[1][bt]);
          }
        }
        __syncthreads();
      }
    }

    // ---- in-register epilogue: lane holds (zi,zf,zg,zo) for (h,b) ----
#pragma unroll
    for (int nt = 0; nt < 2; ++nt)
#pragma unroll
      for (int bt = 0; bt < 4; ++bt) {
        int b = m0 + (bt << 4) + llo;
        int h = hb + (w << 3) + (nt << 2) + lhi;
        float zi = acc[nt][bt][0] + __half2float(__ushort_as_half(zp[nt][bt].x)) + bb[nt].x;
        float zf = acc[nt][bt][1] + __half2float(__ushort_as_half(zp[nt][bt].y)) + bb[nt].y;
        float zg = acc[nt][bt][2] + __half2float(__ushort_as_half(zp[nt][bt].z)) + bb[nt].z;
        float zo = acc[nt][bt][3] + __half2float(__ushort_as_half(zp[nt][bt].w)) + bb[nt].w;
        float ig = sigm(zi);
        float fg = sigm(zf);
        float gg = tanh_(zg);
        float og = sigm(zo);
        float cn = fg * c[nt][bt] + ig * gg;
        c[nt][bt] = cn;
        float hn = og * tanh_(cn);
        // repack h via LDS scratch (wave-local region): [b_local 64][h_local 8]
        Sc[(w << 9) + (((bt << 4) + llo) << 3) + (nt << 2) + lhi] = f2bf(hn);
        out[((size_t)b << 15) + ((size_t)t << 9) + h] = hn;
      }
    asm volatile("s_waitcnt lgkmcnt(0)" ::: "memory");   // scratch writes visible in-wave
    __builtin_amdgcn_sched_barrier(0);
    {
      // one coalesced 16B coherent store per thread: b = m0+lane, h = hb+w*8 .. +8
      u32x4 hv = *(const u32x4*)&Sc[(w << 9) + (lane << 3)];
      st128_coh(&Hbuf[(size_t)((t + 1) & 1) * HSZ + ((size_t)(m0 + lane) << 9) + hb + (w << 3)], hv);
    }
    // As reuse hazard vs next step's staging covered by group_barrier's __syncthreads.
  }
}

extern "C" void kernel_launch(void* const* d_in, const int* in_sizes, int n_in,
                              void* d_out, int out_size, void* d_ws, size_t ws_size,
                              hipStream_t stream) {
  const float* x    = (const float*)d_in[0];   // [1024][64][512]
  const float* Wk   = (const float*)d_in[1];   // [512][2048]
  const float* Wr   = (const float*)d_in[2];   // [512][2048]
  const float* bias = (const float*)d_in[3];   // [2048]
  float* out = (float*)d_out;                  // [1024][64][512]

  char* ws = (char*)d_ws;
  // ws (16B-aligned): Wx 2MiB | Wh 2MiB | biasr 8KB | Hbuf 2x1MiB | bar 4KB | Xbf 64MiB | zx 256MiB
  unsigned short* Wx    = (unsigned short*)(ws);
  unsigned short* Wh    = (unsigned short*)(ws + (2u << 20));
  float*          biasr = (float*)(ws + (4u << 20));
  unsigned short* Hbuf  = (unsigned short*)(ws + (4u << 20) + 8192);
  unsigned int*   bar   = (unsigned int*)(ws + (6u << 20) + 8192);
  unsigned short* Xbf   = (unsigned short*)(ws + (8u << 20) + 8192);
  unsigned short* zx    = (unsigned short*)(ws + (72u << 20) + 8192);

  (void)hipFuncSetAttribute((const void*)lstm_persist,
                            hipFuncAttributeMaxDynamicSharedMemorySize, 151552);

  prep_w<<<dim3(8192), dim3(256), 0, stream>>>(Wk, Wr, bias, Wx, Wh, biasr, bar);
  prep_x<<<dim3(16384), dim3(256), 0, stream>>>(x, Xbf);
  zx_gemm<<<dim3(32, 1024), dim3(256), 0, stream>>>(Xbf, Wx, zx);
  lstm_persist<<<dim3(256), dim3(256), 151552, stream>>>(Hbuf, Wh, zx, biasr, out, bar);
}